// Round 3
// baseline (1192.453 us; speedup 1.0000x reference)
//
#include <hip/hip_runtime.h>

// ---------------------------------------------------------------------------
// Structure_Diffusion: pooled-token attention gates + two gated 3x3 convs.
//  R2 counters: conv_gemm 446us latency-bound (Mfma 15.7%, HBM 12%, occ 18.7)
//               attn ~440us scalar-LDS-bound (8 blocks).
//  R3: conv_gemm -> depth-2 counted-vmcnt pipeline (wait vmcnt(6), never 0 in
//      steady state; fused asm waitcnt+s_barrier blocks = compiler fences).
//      attn -> float4 dots + W2[k][m] factoring (h = W2 @ y), pure fp32.
// ---------------------------------------------------------------------------

#define BATCH 8
#define CH    256
#define HH    96
#define WW    96
#define HWA   9216      // 96*96
#define NP    57
#define PH    98        // padded spatial
#define KTOT  2304      // 9*256
#define NCHUNK 72       // KTOT/32
#define OUTHALF (BATCH*CH*HWA)  // 18874368
#define YSTR  260       // y row stride in attn LDS (16B-aligned: 260*4%16==0)

typedef short  short8  __attribute__((ext_vector_type(8)));
typedef float  float4f __attribute__((ext_vector_type(4)));
typedef unsigned short us4 __attribute__((ext_vector_type(4)));

__device__ __forceinline__ unsigned short f2bf(float f) {
    unsigned int u = __float_as_uint(f);
    u += 0x7fffu + ((u >> 16) & 1u);   // RNE
    return (unsigned short)(u >> 16);
}

#define GLDS16(gp, sp) __builtin_amdgcn_global_load_lds( \
    (const __attribute__((address_space(1))) void*)(gp),  \
    (__attribute__((address_space(3))) void*)(sp), 16, 0, 0)

// ---------------------------------------------------------------------------
// K1: pool x1/x2 into 57 block-means per (b,c).  grid (256 c, 8 b, 2 input)
// ---------------------------------------------------------------------------
__global__ void pool_kernel(const float* __restrict__ x1,
                            const float* __restrict__ x2,
                            float* __restrict__ px) {
    int c = blockIdx.x, b = blockIdx.y, z = blockIdx.z;
    const float* src = (z ? x2 : x1) + ((long)b * CH + c) * HWA;
    __shared__ float seg[1152];   // [row 96][colblock 12]
    __shared__ float bins[144];   // 12x12 grid of 8x8 block sums
    int t = threadIdx.x;
    for (int s = t; s < 1152; s += 256) {
        int r = s / 12, cb = s - r * 12;
        const float4f* p = (const float4f*)(src + r * 96 + cb * 8);
        float4f a = p[0], bv = p[1];
        seg[s] = (a.x + a.y) + (a.z + a.w) + (bv.x + bv.y) + (bv.z + bv.w);
    }
    __syncthreads();
    if (t < 144) {
        int i = t / 12, j = t - i * 12;
        float s = 0.f;
#pragma unroll
        for (int r = 0; r < 8; ++r) s += seg[(i * 8 + r) * 12 + j];
        bins[t] = s;
    }
    __syncthreads();
    if (t < NP) {
        int bh0, bw0, nb;
        if (t == 0)      { bh0 = 0; bw0 = 0; nb = 12; }
        else if (t < 5)  { int q = t - 1;  bh0 = (q >> 1) * 6; bw0 = (q & 1) * 6; nb = 6; }
        else if (t < 21) { int q = t - 5;  bh0 = (q >> 2) * 3; bw0 = (q & 3) * 3; nb = 3; }
        else             { int q = t - 21; bh0 = (q / 6) * 2;  bw0 = (q % 6) * 2; nb = 2; }
        float s = 0.f;
        for (int i = 0; i < nb; ++i)
            for (int j = 0; j < nb; ++j)
                s += bins[(bh0 + i) * 12 + (bw0 + j)];
        px[(((long)z * BATCH + b) * CH + c) * NP + t] = s / (float)(nb * nb * 64);
    }
}

// ---------------------------------------------------------------------------
// K2: y[z,b,n,c] = normalize_c( BN(conv1x1(px)) ).  grid (57 n, 8 b, 2 z)
// ---------------------------------------------------------------------------
__global__ void ycomp_kernel(const float* __restrict__ px,
    const float* __restrict__ w3, const float* __restrict__ cb3,
    const float* __restrict__ g3, const float* __restrict__ be3,
    const float* __restrict__ m3, const float* __restrict__ v3,
    const float* __restrict__ w4, const float* __restrict__ cb4,
    const float* __restrict__ g4, const float* __restrict__ be4,
    const float* __restrict__ m4, const float* __restrict__ v4,
    float* __restrict__ y) {
    int n = blockIdx.x, b = blockIdx.y, z = blockIdx.z;
    __shared__ float col[CH];
    __shared__ float red[CH];
    int c = threadIdx.x;
    col[c] = px[(((long)z * BATCH + b) * CH + c) * NP + n];
    __syncthreads();
    const float* w  = z ? w4  : w3;
    const float* cb = z ? cb4 : cb3;
    const float* gg = z ? g4  : g3;
    const float* be = z ? be4 : be3;
    const float* mm = z ? m4  : m3;
    const float* vv = z ? v4  : v3;
    float s = gg[c] * rsqrtf(vv[c] + 1e-5f);
    const float4f* wr4  = (const float4f*)(w + (long)c * CH);
    const float4f* col4 = (const float4f*)col;
    float4f a4 = {0.f, 0.f, 0.f, 0.f};
#pragma unroll 8
    for (int ci = 0; ci < CH / 4; ++ci) a4 += wr4[ci] * col4[ci];
    float acc = (a4.x + a4.y) + (a4.z + a4.w);
    float yv = s * acc + (cb[c] - mm[c]) * s + be[c];
    red[c] = yv * yv;
    __syncthreads();
    for (int st = 128; st > 0; st >>= 1) {
        if (c < st) red[c] += red[c + st];
        __syncthreads();
    }
    float scale = 1.f / fmaxf(sqrtf(red[0]), 1e-12f);
    y[(((long)z * BATCH + b) * NP + n) * CH + c] = yv * scale;
}

// ---------------------------------------------------------------------------
// K3: per-batch attention + fc3 -> gates[2][8][256].  grid (8), 256 thr
//  float4 dot-products; h[k][c] = sum_m W2[k][m]*y[m][c] with
//  W2[k][m] = sum_n w31[k][n]*softmax(l)[n][m]  (g never materialized)
// ---------------------------------------------------------------------------
__global__ void attn_kernel(const float* __restrict__ y,
    const float* __restrict__ fw1, const float* __restrict__ fb1,
    const float* __restrict__ fw2, const float* __restrict__ fb2,
    const float* __restrict__ w31, const float* __restrict__ b31,
    const float* __restrict__ w32, const float* __restrict__ b32,
    float* __restrict__ gates) {
    int b = blockIdx.x, t = threadIdx.x;
    __shared__ __align__(16) float y1s[NP * YSTR];
    __shared__ __align__(16) float y2s[NP * YSTR];
    __shared__ float l1[NP * NP];
    __shared__ float l2[NP * NP];
    __shared__ float w31s[16 * NP];
    __shared__ float W21[16 * NP];
    __shared__ float W22[16 * NP];
    const float* y1g = y + (long)b * NP * CH;
    const float* y2g = y + (long)(BATCH + b) * NP * CH;
    for (int i = t; i < NP * 64; i += 256) {     // 64 float4 per row
        int n = i >> 6, cq = i & 63;
        *(float4f*)&y1s[n * YSTR + cq * 4] = *(const float4f*)&y1g[n * CH + cq * 4];
        *(float4f*)&y2s[n * YSTR + cq * 4] = *(const float4f*)&y2g[n * CH + cq * 4];
    }
    for (int i = t; i < 16 * NP; i += 256) w31s[i] = w31[i];
    __syncthreads();
    float a10 = fw1[0], a11 = fw1[1], a12 = fw1[2], a13 = fw1[3], b1v = fb1[0];
    float a20 = fw2[0], a21 = fw2[1], a22 = fw2[2], a23 = fw2[3], b2v = fb2[0];
    int p0 = (t & 7) * 8;                        // bank-stagger start
    for (int idx = t; idx < NP * NP; idx += 256) {
        int n = idx / NP, m = idx - n * NP;
        const float4f* yn1 = (const float4f*)&y1s[n * YSTR];
        const float4f* ym1 = (const float4f*)&y1s[m * YSTR];
        const float4f* yn2 = (const float4f*)&y2s[n * YSTR];
        const float4f* ym2 = (const float4f*)&y2s[m * YSTR];
        float4f d1 = {0,0,0,0}, d2 = {0,0,0,0}, d12 = {0,0,0,0};
        for (int q = 0; q < 64; ++q) {
            int cq = (q + p0) & 63;
            float4f a1 = yn1[cq], bb1 = ym1[cq];
            float4f a2 = yn2[cq], bb2 = ym2[cq];
            d1 += a1 * bb1; d2 += a2 * bb2; d12 += a1 * bb2;
        }
        float dd1 = (d1.x + d1.y) + (d1.z + d1.w);
        float dd2 = (d2.x + d2.y) + (d2.z + d2.w);
        float dd12 = (d12.x + d12.y) + (d12.z + d12.w);
        float s1 = 1.f - dd1, s2 = 1.f - dd2, s12 = 1.f - dd12;
        l1[idx] = a10 * s1 + a11 * s2 + a12 * s1 * s2 + a13 * s12 + b1v;
        l2[idx] = a20 * s1 + a21 * s2 + a22 * s1 * s2 + a23 * s12 + b2v;
    }
    __syncthreads();
    if (t < 2 * NP) {    // softmax rows (both branches)
        int which = t >= NP;
        int n = which ? t - NP : t;
        float* l = which ? l2 : l1;
        float mx = -1e30f;
        for (int m = 0; m < NP; ++m) mx = fmaxf(mx, l[n * NP + m]);
        float sum = 0.f;
        for (int m = 0; m < NP; ++m) { float e = __expf(l[n * NP + m] - mx); l[n * NP + m] = e; sum += e; }
        float inv = 1.f / sum;
        for (int m = 0; m < NP; ++m) l[n * NP + m] *= inv;
    }
    __syncthreads();
    // W2[k][m] = sum_n w31[k][n] * l[n][m]
    for (int i = t; i < 16 * NP; i += 256) {
        int k = i / NP, m = i - k * NP;
        float s1 = 0.f, s2 = 0.f;
        for (int n = 0; n < NP; ++n) {
            float wv = w31s[k * NP + n];
            s1 += wv * l1[n * NP + m];
            s2 += wv * l2[n * NP + m];
        }
        W21[i] = s1; W22[i] = s2;
    }
    __syncthreads();
    int c = t;
    float h1[16], h2[16];
#pragma unroll
    for (int k = 0; k < 16; ++k) { h1[k] = 0.f; h2[k] = 0.f; }
    for (int m = 0; m < NP; ++m) {
        float ym1 = y1s[m * YSTR + c];
        float ym2 = y2s[m * YSTR + c];
#pragma unroll
        for (int k = 0; k < 16; ++k) {
            h1[k] += W21[k * NP + m] * ym1;
            h2[k] += W22[k * NP + m] * ym2;
        }
    }
    float o1 = b32[0], o2 = b32[0];
#pragma unroll
    for (int k = 0; k < 16; ++k) {
        float wk = w32[k];
        o1 += wk * (h1[k] + b31[k]);
        o2 += wk * (h2[k] + b31[k]);
    }
    gates[b * CH + c]        = 1.f / (1.f + __expf(-o1));
    gates[2048 + b * CH + c] = 1.f / (1.f + __expf(-o2));
}

// ---------------------------------------------------------------------------
// K4: prepack conv1/conv2 weights (BN scale folded) -> Wp[which][co][k] bf16
// ---------------------------------------------------------------------------
__global__ void prepack_kernel(
    const float* __restrict__ w1, const float* __restrict__ cb1,
    const float* __restrict__ g1, const float* __restrict__ be1,
    const float* __restrict__ m1, const float* __restrict__ v1,
    const float* __restrict__ w2, const float* __restrict__ cb2,
    const float* __restrict__ g2, const float* __restrict__ be2,
    const float* __restrict__ m2, const float* __restrict__ v2,
    unsigned short* __restrict__ Wp, float* __restrict__ bias) {
    long idx = (long)blockIdx.x * 256 + threadIdx.x;   // 0 .. 2*256*2304-1
    int which = idx >= (long)CH * KTOT;
    long rem = idx - (long)which * CH * KTOT;
    int co = (int)(rem / KTOT);
    int k  = (int)(rem - (long)co * KTOT);
    int r = k >> 8, ci = k & 255;
    int dy = r / 3, dx = r - dy * 3;
    const float* w  = which ? w2  : w1;
    const float* cb = which ? cb2 : cb1;
    const float* gg = which ? g2  : g1;
    const float* be = which ? be2 : be1;
    const float* mm = which ? m2  : m1;
    const float* vv = which ? v2  : v1;
    float s = gg[co] * rsqrtf(vv[co] + 1e-5f);
    float val = w[(((long)co * CH + ci) * 3 + dy) * 3 + dx] * s;
    Wp[idx] = f2bf(val);
    if (k == 0) bias[which * CH + co] = (cb[co] - mm[co]) * s + be[co];
}

// ---------------------------------------------------------------------------
// K5: pad+transpose x3/x4 -> channels-last padded bf16 (8,98,98,256).
// ---------------------------------------------------------------------------
__global__ void pad_kernel(const float* __restrict__ x3,
                           const float* __restrict__ x4,
                           unsigned short* __restrict__ xp3,
                           unsigned short* __restrict__ xp4) {
    int hp = blockIdx.x, b = blockIdx.y, z = blockIdx.z;
    const float* src = z ? x4 : x3;
    unsigned short* dst = z ? xp4 : xp3;
    __shared__ float buf[64][97];
    int t = threadIdx.x;
    bool border = (hp == 0 || hp == PH - 1);
    int h = hp - 1;
    for (int ci0 = 0; ci0 < CH; ci0 += 64) {
        if (!border) {
            for (int idx = t; idx < 64 * 96; idx += 256) {
                int cl = idx / 96, w = idx - cl * 96;
                buf[cl][w] = src[(((long)b * CH + ci0 + cl) * HH + h) * WW + w];
            }
        }
        __syncthreads();
        for (int idx = t; idx < PH * 16; idx += 256) {
            int wp = idx >> 4, cq = idx & 15;
            us4 v = {0, 0, 0, 0};
            if (!border && wp >= 1 && wp <= 96) {
                int wq = wp - 1;
                v.x = f2bf(buf[cq * 4 + 0][wq]);
                v.y = f2bf(buf[cq * 4 + 1][wq]);
                v.z = f2bf(buf[cq * 4 + 2][wq]);
                v.w = f2bf(buf[cq * 4 + 3][wq]);
            }
            *(us4*)&dst[(((long)b * PH + hp) * PH + wp) * CH + ci0 + cq * 4] = v;
        }
        __syncthreads();
    }
}

// ---------------------------------------------------------------------------
// K6: gated 3x3 conv, implicit bf16 MFMA GEMM, depth-2 counted-vmcnt pipeline.
//   Loop invariant: 12 vm-ops outstanding per wave at entry (bufs kc, kc+1).
//   wait vmcnt(6) -> buf[cur] complete; compute; lgkmcnt(0)+barrier; STAGE
//   kc+2 into buf[cur].  Fused asm (waitcnt+s_barrier, "memory") = fences.
// ---------------------------------------------------------------------------
__global__ __launch_bounds__(256, 3)
void conv_gemm(const unsigned short* __restrict__ xp3,
               const unsigned short* __restrict__ xp4,
               const unsigned short* __restrict__ Wp0,
               const float* __restrict__ gates,
               const float* __restrict__ bias2,
               const float* __restrict__ x3,
               const float* __restrict__ x4,
               float* __restrict__ outg) {
    int zc = blockIdx.y;
    const unsigned short* xp = zc ? xp3 : xp4;
    const unsigned short* Wp = Wp0 + (long)zc * CH * KTOT;
    const float* gate  = gates + (long)zc * 2048;
    const float* bias  = bias2 + zc * CH;
    const float* resid = zc ? x4 : x3;
    float* out = outg + (long)zc * OUTHALF;

    __shared__ short As[2][4 * 128 * 8];   // 2 x 8 KB
    __shared__ short Bs[2][4 * 256 * 8];   // 2 x 16 KB
    int tid = threadIdx.x;
    // XCD-chunked bijective swizzle (576 % 8 == 0): XCD k owns image k.
    int bm0 = blockIdx.x;
    int bm = (bm0 & 7) * 72 + (bm0 >> 3);
    int bimg = bm / 72, tt = bm - bimg * 72;
    int h0 = (tt / 6) * 8, w0 = (tt % 6) * 16;

    int lane = tid & 63, wid = tid >> 6;
    int wm = wid & 1, wn = wid >> 1;
    int lm = lane & 15, quad = lane >> 4;

    long apix0 = ((long)(bimg * PH + h0 + (lane >> 4)) * PH + (w0 + (lane & 15))) * CH + wid * 8;
    long apix1 = ((long)(bimg * PH + h0 + 4 + (lane >> 4)) * PH + (w0 + (lane & 15))) * CH + wid * 8;
    long bb0 = (long)(lane) * KTOT + wid * 8;
    long bb1 = (long)(64 + lane) * KTOT + wid * 8;
    long bb2 = (long)(128 + lane) * KTOT + wid * 8;
    long bb3 = (long)(192 + lane) * KTOT + wid * 8;

    float4f acc[4][8] = {};

    auto STAGE = [&](int buf, int kc) {
        int r9 = kc >> 3;
        int dy = r9 / 3, dx = r9 - dy * 3;
        long aoff = (long)(dy * PH + dx) * CH + ((kc & 7) << 5);
        long boff = (long)kc << 5;
        short* asd = &As[buf][wid * 1024];
        short* bsd = &Bs[buf][wid * 2048];
        GLDS16(xp + apix0 + aoff, asd);
        GLDS16(xp + apix1 + aoff, asd + 512);
        GLDS16(Wp + bb0 + boff, bsd);
        GLDS16(Wp + bb1 + boff, bsd + 512);
        GLDS16(Wp + bb2 + boff, bsd + 1024);
        GLDS16(Wp + bb3 + boff, bsd + 1536);
    };

    STAGE(0, 0);
    STAGE(1, 1);
    int cur = 0;
    for (int kc = 0; kc < NCHUNK; ++kc) {
        if (kc + 1 < NCHUNK) {
            asm volatile("s_waitcnt vmcnt(6)\n\ts_barrier" ::: "memory");
        } else {
            asm volatile("s_waitcnt vmcnt(0)\n\ts_barrier" ::: "memory");
        }
        short8 af[4], bfr[8];
#pragma unroll
        for (int i = 0; i < 4; ++i)
            af[i] = *(short8*)&As[cur][quad * 1024 + (wm * 64 + i * 16 + lm) * 8];
#pragma unroll
        for (int j = 0; j < 8; ++j)
            bfr[j] = *(short8*)&Bs[cur][quad * 2048 + (wn * 128 + j * 16 + lm) * 8];
#pragma unroll
        for (int i = 0; i < 4; ++i)
#pragma unroll
            for (int j = 0; j < 8; ++j)
                acc[i][j] = __builtin_amdgcn_mfma_f32_16x16x32_bf16(af[i], bfr[j], acc[i][j], 0, 0, 0);
        asm volatile("s_waitcnt lgkmcnt(0)\n\ts_barrier" ::: "memory");
        if (kc + 2 < NCHUNK) STAGE(cur, kc + 2);
        cur ^= 1;
    }

    // epilogue: D row = quad*4+reg (pixel w-offset), col = lane&15 (co)
#pragma unroll
    for (int j = 0; j < 8; ++j) {
        int co = wn * 128 + j * 16 + lm;
        float g  = gate[bimg * CH + co];
        float bv = bias[co];
#pragma unroll
        for (int i = 0; i < 4; ++i) {
            int h = h0 + wm * 4 + i;
            int w = w0 + quad * 4;
            long o = ((long)(bimg * CH + co)) * HWA + h * WW + w;
            float4f rv = *(const float4f*)(resid + o);
            float4f ov = rv + g * (acc[i][j] + bv);
            *(float4f*)(out + o) = ov;
        }
    }
}

// ---------------------------------------------------------------------------
extern "C" void kernel_launch(void* const* d_in, const int* in_sizes, int n_in,
                              void* d_out, int out_size, void* d_ws, size_t ws_size,
                              hipStream_t stream) {
    const float* x1 = (const float*)d_in[0];
    const float* x2 = (const float*)d_in[1];
    const float* x3 = (const float*)d_in[2];
    const float* x4 = (const float*)d_in[3];
    const float* conv3_w = (const float*)d_in[4];
    const float* conv3_b = (const float*)d_in[5];
    const float* bn3_g = (const float*)d_in[6];
    const float* bn3_b = (const float*)d_in[7];
    const float* bn3_m = (const float*)d_in[8];
    const float* bn3_v = (const float*)d_in[9];
    const float* conv4_w = (const float*)d_in[10];
    const float* conv4_b = (const float*)d_in[11];
    const float* bn4_g = (const float*)d_in[12];
    const float* bn4_b = (const float*)d_in[13];
    const float* bn4_m = (const float*)d_in[14];
    const float* bn4_v = (const float*)d_in[15];
    const float* conv1_w = (const float*)d_in[16];
    const float* conv1_b = (const float*)d_in[17];
    const float* bn1_g = (const float*)d_in[18];
    const float* bn1_b = (const float*)d_in[19];
    const float* bn1_m = (const float*)d_in[20];
    const float* bn1_v = (const float*)d_in[21];
    const float* conv2_w = (const float*)d_in[22];
    const float* conv2_b = (const float*)d_in[23];
    const float* bn2_g = (const float*)d_in[24];
    const float* bn2_b = (const float*)d_in[25];
    const float* bn2_m = (const float*)d_in[26];
    const float* bn2_v = (const float*)d_in[27];
    const float* fc1_w = (const float*)d_in[28];
    const float* fc1_b = (const float*)d_in[29];
    const float* fc2_w = (const float*)d_in[30];
    const float* fc2_b = (const float*)d_in[31];
    const float* fc3_w1 = (const float*)d_in[32];
    const float* fc3_b1 = (const float*)d_in[33];
    const float* fc3_w2 = (const float*)d_in[34];
    const float* fc3_b2 = (const float*)d_in[35];

    float* ws = (float*)d_ws;
    float* px    = ws;                 // 2*8*256*57 = 233472 floats
    float* y     = ws + 233472;        // 233472 floats
    float* gates = ws + 466944;        // 2*8*256 = 4096
    float* bias  = ws + 471040;        // 2*256 = 512
    unsigned short* Wp  = (unsigned short*)(ws + 471552);   // 2*256*2304 shorts
    unsigned short* xp3 = Wp + 2 * CH * KTOT;               // 8*98*98*256 shorts
    unsigned short* xp4 = xp3 + (long)BATCH * PH * PH * CH;

    pool_kernel<<<dim3(256, 8, 2), 256, 0, stream>>>(x1, x2, px);
    ycomp_kernel<<<dim3(57, 8, 2), 256, 0, stream>>>(px,
        conv3_w, conv3_b, bn3_g, bn3_b, bn3_m, bn3_v,
        conv4_w, conv4_b, bn4_g, bn4_b, bn4_m, bn4_v, y);
    attn_kernel<<<dim3(8), 256, 0, stream>>>(y, fc1_w, fc1_b, fc2_w, fc2_b,
        fc3_w1, fc3_b1, fc3_w2, fc3_b2, gates);
    prepack_kernel<<<dim3(4608), 256, 0, stream>>>(
        conv1_w, conv1_b, bn1_g, bn1_b, bn1_m, bn1_v,
        conv2_w, conv2_b, bn2_g, bn2_b, bn2_m, bn2_v, Wp, bias);
    pad_kernel<<<dim3(PH, 8, 2), 256, 0, stream>>>(x3, x4, xp3, xp4);

    // z=0: x3_out = x3 + gate1*BN1(conv1(x4)); z=1: x4_out = x4 + gate2*BN2(conv2(x3))
    conv_gemm<<<dim3(576, 2), 256, 0, stream>>>(xp3, xp4, Wp, gates, bias,
        x3, x4, (float*)d_out);
}

// Round 4
// 930.087 us; speedup vs baseline: 1.2821x; 1.2821x over previous
//
#include <hip/hip_runtime.h>

// ---------------------------------------------------------------------------
// Structure_Diffusion: pooled-token attention gates + two gated 3x3 convs.
//  R2 counters: conv_gemm 446us latency-bound (Mfma 15.7%, HBM 12%, occ 18.7)
//  R3 FAILED: __launch_bounds__(256,3) -> 84 VGPR -> acc spilled to scratch
//     (WRITE_SIZE +136MB, FETCH +227MB, 657us).  Pipeline never got tested.
//  R4: depth-2 counted-vmcnt pipeline + __launch_bounds__(256,2) (128 VGPR,
//      no spill).  Only variable vs R2 = the pipeline.
// ---------------------------------------------------------------------------

#define BATCH 8
#define CH    256
#define HH    96
#define WW    96
#define HWA   9216      // 96*96
#define NP    57
#define PH    98        // padded spatial
#define KTOT  2304      // 9*256
#define NCHUNK 72       // KTOT/32
#define OUTHALF (BATCH*CH*HWA)  // 18874368
#define YSTR  260       // y row stride in attn LDS (16B-aligned: 260*4%16==0)

typedef short  short8  __attribute__((ext_vector_type(8)));
typedef float  float4f __attribute__((ext_vector_type(4)));
typedef unsigned short us4 __attribute__((ext_vector_type(4)));

__device__ __forceinline__ unsigned short f2bf(float f) {
    unsigned int u = __float_as_uint(f);
    u += 0x7fffu + ((u >> 16) & 1u);   // RNE
    return (unsigned short)(u >> 16);
}

#define GLDS16(gp, sp) __builtin_amdgcn_global_load_lds( \
    (const __attribute__((address_space(1))) void*)(gp),  \
    (__attribute__((address_space(3))) void*)(sp), 16, 0, 0)

// ---------------------------------------------------------------------------
// K1: pool x1/x2 into 57 block-means per (b,c).  grid (256 c, 8 b, 2 input)
// ---------------------------------------------------------------------------
__global__ void pool_kernel(const float* __restrict__ x1,
                            const float* __restrict__ x2,
                            float* __restrict__ px) {
    int c = blockIdx.x, b = blockIdx.y, z = blockIdx.z;
    const float* src = (z ? x2 : x1) + ((long)b * CH + c) * HWA;
    __shared__ float seg[1152];   // [row 96][colblock 12]
    __shared__ float bins[144];   // 12x12 grid of 8x8 block sums
    int t = threadIdx.x;
    for (int s = t; s < 1152; s += 256) {
        int r = s / 12, cb = s - r * 12;
        const float4f* p = (const float4f*)(src + r * 96 + cb * 8);
        float4f a = p[0], bv = p[1];
        seg[s] = (a.x + a.y) + (a.z + a.w) + (bv.x + bv.y) + (bv.z + bv.w);
    }
    __syncthreads();
    if (t < 144) {
        int i = t / 12, j = t - i * 12;
        float s = 0.f;
#pragma unroll
        for (int r = 0; r < 8; ++r) s += seg[(i * 8 + r) * 12 + j];
        bins[t] = s;
    }
    __syncthreads();
    if (t < NP) {
        int bh0, bw0, nb;
        if (t == 0)      { bh0 = 0; bw0 = 0; nb = 12; }
        else if (t < 5)  { int q = t - 1;  bh0 = (q >> 1) * 6; bw0 = (q & 1) * 6; nb = 6; }
        else if (t < 21) { int q = t - 5;  bh0 = (q >> 2) * 3; bw0 = (q & 3) * 3; nb = 3; }
        else             { int q = t - 21; bh0 = (q / 6) * 2;  bw0 = (q % 6) * 2; nb = 2; }
        float s = 0.f;
        for (int i = 0; i < nb; ++i)
            for (int j = 0; j < nb; ++j)
                s += bins[(bh0 + i) * 12 + (bw0 + j)];
        px[(((long)z * BATCH + b) * CH + c) * NP + t] = s / (float)(nb * nb * 64);
    }
}

// ---------------------------------------------------------------------------
// K2: y[z,b,n,c] = normalize_c( BN(conv1x1(px)) ).  grid (57 n, 8 b, 2 z)
// ---------------------------------------------------------------------------
__global__ void ycomp_kernel(const float* __restrict__ px,
    const float* __restrict__ w3, const float* __restrict__ cb3,
    const float* __restrict__ g3, const float* __restrict__ be3,
    const float* __restrict__ m3, const float* __restrict__ v3,
    const float* __restrict__ w4, const float* __restrict__ cb4,
    const float* __restrict__ g4, const float* __restrict__ be4,
    const float* __restrict__ m4, const float* __restrict__ v4,
    float* __restrict__ y) {
    int n = blockIdx.x, b = blockIdx.y, z = blockIdx.z;
    __shared__ float col[CH];
    __shared__ float red[CH];
    int c = threadIdx.x;
    col[c] = px[(((long)z * BATCH + b) * CH + c) * NP + n];
    __syncthreads();
    const float* w  = z ? w4  : w3;
    const float* cb = z ? cb4 : cb3;
    const float* gg = z ? g4  : g3;
    const float* be = z ? be4 : be3;
    const float* mm = z ? m4  : m3;
    const float* vv = z ? v4  : v3;
    float s = gg[c] * rsqrtf(vv[c] + 1e-5f);
    const float4f* wr4  = (const float4f*)(w + (long)c * CH);
    const float4f* col4 = (const float4f*)col;
    float4f a4 = {0.f, 0.f, 0.f, 0.f};
#pragma unroll 8
    for (int ci = 0; ci < CH / 4; ++ci) a4 += wr4[ci] * col4[ci];
    float acc = (a4.x + a4.y) + (a4.z + a4.w);
    float yv = s * acc + (cb[c] - mm[c]) * s + be[c];
    red[c] = yv * yv;
    __syncthreads();
    for (int st = 128; st > 0; st >>= 1) {
        if (c < st) red[c] += red[c + st];
        __syncthreads();
    }
    float scale = 1.f / fmaxf(sqrtf(red[0]), 1e-12f);
    y[(((long)z * BATCH + b) * NP + n) * CH + c] = yv * scale;
}

// ---------------------------------------------------------------------------
// K3: per-batch attention + fc3 -> gates[2][8][256].  grid (8), 256 thr
//  float4 dot-products; h[k][c] = sum_m W2[k][m]*y[m][c] with
//  W2[k][m] = sum_n w31[k][n]*softmax(l)[n][m]  (g never materialized)
// ---------------------------------------------------------------------------
__global__ void attn_kernel(const float* __restrict__ y,
    const float* __restrict__ fw1, const float* __restrict__ fb1,
    const float* __restrict__ fw2, const float* __restrict__ fb2,
    const float* __restrict__ w31, const float* __restrict__ b31,
    const float* __restrict__ w32, const float* __restrict__ b32,
    float* __restrict__ gates) {
    int b = blockIdx.x, t = threadIdx.x;
    __shared__ __align__(16) float y1s[NP * YSTR];
    __shared__ __align__(16) float y2s[NP * YSTR];
    __shared__ float l1[NP * NP];
    __shared__ float l2[NP * NP];
    __shared__ float w31s[16 * NP];
    __shared__ float W21[16 * NP];
    __shared__ float W22[16 * NP];
    const float* y1g = y + (long)b * NP * CH;
    const float* y2g = y + (long)(BATCH + b) * NP * CH;
    for (int i = t; i < NP * 64; i += 256) {     // 64 float4 per row
        int n = i >> 6, cq = i & 63;
        *(float4f*)&y1s[n * YSTR + cq * 4] = *(const float4f*)&y1g[n * CH + cq * 4];
        *(float4f*)&y2s[n * YSTR + cq * 4] = *(const float4f*)&y2g[n * CH + cq * 4];
    }
    for (int i = t; i < 16 * NP; i += 256) w31s[i] = w31[i];
    __syncthreads();
    float a10 = fw1[0], a11 = fw1[1], a12 = fw1[2], a13 = fw1[3], b1v = fb1[0];
    float a20 = fw2[0], a21 = fw2[1], a22 = fw2[2], a23 = fw2[3], b2v = fb2[0];
    int p0 = (t & 7) * 8;                        // bank-stagger start
    for (int idx = t; idx < NP * NP; idx += 256) {
        int n = idx / NP, m = idx - n * NP;
        const float4f* yn1 = (const float4f*)&y1s[n * YSTR];
        const float4f* ym1 = (const float4f*)&y1s[m * YSTR];
        const float4f* yn2 = (const float4f*)&y2s[n * YSTR];
        const float4f* ym2 = (const float4f*)&y2s[m * YSTR];
        float4f d1 = {0,0,0,0}, d2 = {0,0,0,0}, d12 = {0,0,0,0};
        for (int q = 0; q < 64; ++q) {
            int cq = (q + p0) & 63;
            float4f a1 = yn1[cq], bb1 = ym1[cq];
            float4f a2 = yn2[cq], bb2 = ym2[cq];
            d1 += a1 * bb1; d2 += a2 * bb2; d12 += a1 * bb2;
        }
        float dd1 = (d1.x + d1.y) + (d1.z + d1.w);
        float dd2 = (d2.x + d2.y) + (d2.z + d2.w);
        float dd12 = (d12.x + d12.y) + (d12.z + d12.w);
        float s1 = 1.f - dd1, s2 = 1.f - dd2, s12 = 1.f - dd12;
        l1[idx] = a10 * s1 + a11 * s2 + a12 * s1 * s2 + a13 * s12 + b1v;
        l2[idx] = a20 * s1 + a21 * s2 + a22 * s1 * s2 + a23 * s12 + b2v;
    }
    __syncthreads();
    if (t < 2 * NP) {    // softmax rows (both branches)
        int which = t >= NP;
        int n = which ? t - NP : t;
        float* l = which ? l2 : l1;
        float mx = -1e30f;
        for (int m = 0; m < NP; ++m) mx = fmaxf(mx, l[n * NP + m]);
        float sum = 0.f;
        for (int m = 0; m < NP; ++m) { float e = __expf(l[n * NP + m] - mx); l[n * NP + m] = e; sum += e; }
        float inv = 1.f / sum;
        for (int m = 0; m < NP; ++m) l[n * NP + m] *= inv;
    }
    __syncthreads();
    // W2[k][m] = sum_n w31[k][n] * l[n][m]
    for (int i = t; i < 16 * NP; i += 256) {
        int k = i / NP, m = i - k * NP;
        float s1 = 0.f, s2 = 0.f;
        for (int n = 0; n < NP; ++n) {
            float wv = w31s[k * NP + n];
            s1 += wv * l1[n * NP + m];
            s2 += wv * l2[n * NP + m];
        }
        W21[i] = s1; W22[i] = s2;
    }
    __syncthreads();
    int c = t;
    float h1[16], h2[16];
#pragma unroll
    for (int k = 0; k < 16; ++k) { h1[k] = 0.f; h2[k] = 0.f; }
    for (int m = 0; m < NP; ++m) {
        float ym1 = y1s[m * YSTR + c];
        float ym2 = y2s[m * YSTR + c];
#pragma unroll
        for (int k = 0; k < 16; ++k) {
            h1[k] += W21[k * NP + m] * ym1;
            h2[k] += W22[k * NP + m] * ym2;
        }
    }
    float o1 = b32[0], o2 = b32[0];
#pragma unroll
    for (int k = 0; k < 16; ++k) {
        float wk = w32[k];
        o1 += wk * (h1[k] + b31[k]);
        o2 += wk * (h2[k] + b31[k]);
    }
    gates[b * CH + c]        = 1.f / (1.f + __expf(-o1));
    gates[2048 + b * CH + c] = 1.f / (1.f + __expf(-o2));
}

// ---------------------------------------------------------------------------
// K4: prepack conv1/conv2 weights (BN scale folded) -> Wp[which][co][k] bf16
// ---------------------------------------------------------------------------
__global__ void prepack_kernel(
    const float* __restrict__ w1, const float* __restrict__ cb1,
    const float* __restrict__ g1, const float* __restrict__ be1,
    const float* __restrict__ m1, const float* __restrict__ v1,
    const float* __restrict__ w2, const float* __restrict__ cb2,
    const float* __restrict__ g2, const float* __restrict__ be2,
    const float* __restrict__ m2, const float* __restrict__ v2,
    unsigned short* __restrict__ Wp, float* __restrict__ bias) {
    long idx = (long)blockIdx.x * 256 + threadIdx.x;   // 0 .. 2*256*2304-1
    int which = idx >= (long)CH * KTOT;
    long rem = idx - (long)which * CH * KTOT;
    int co = (int)(rem / KTOT);
    int k  = (int)(rem - (long)co * KTOT);
    int r = k >> 8, ci = k & 255;
    int dy = r / 3, dx = r - dy * 3;
    const float* w  = which ? w2  : w1;
    const float* cb = which ? cb2 : cb1;
    const float* gg = which ? g2  : g1;
    const float* be = which ? be2 : be1;
    const float* mm = which ? m2  : m1;
    const float* vv = which ? v2  : v1;
    float s = gg[co] * rsqrtf(vv[co] + 1e-5f);
    float val = w[(((long)co * CH + ci) * 3 + dy) * 3 + dx] * s;
    Wp[idx] = f2bf(val);
    if (k == 0) bias[which * CH + co] = (cb[co] - mm[co]) * s + be[co];
}

// ---------------------------------------------------------------------------
// K5: pad+transpose x3/x4 -> channels-last padded bf16 (8,98,98,256).
// ---------------------------------------------------------------------------
__global__ void pad_kernel(const float* __restrict__ x3,
                           const float* __restrict__ x4,
                           unsigned short* __restrict__ xp3,
                           unsigned short* __restrict__ xp4) {
    int hp = blockIdx.x, b = blockIdx.y, z = blockIdx.z;
    const float* src = z ? x4 : x3;
    unsigned short* dst = z ? xp4 : xp3;
    __shared__ float buf[64][97];
    int t = threadIdx.x;
    bool border = (hp == 0 || hp == PH - 1);
    int h = hp - 1;
    for (int ci0 = 0; ci0 < CH; ci0 += 64) {
        if (!border) {
            for (int idx = t; idx < 64 * 96; idx += 256) {
                int cl = idx / 96, w = idx - cl * 96;
                buf[cl][w] = src[(((long)b * CH + ci0 + cl) * HH + h) * WW + w];
            }
        }
        __syncthreads();
        for (int idx = t; idx < PH * 16; idx += 256) {
            int wp = idx >> 4, cq = idx & 15;
            us4 v = {0, 0, 0, 0};
            if (!border && wp >= 1 && wp <= 96) {
                int wq = wp - 1;
                v.x = f2bf(buf[cq * 4 + 0][wq]);
                v.y = f2bf(buf[cq * 4 + 1][wq]);
                v.z = f2bf(buf[cq * 4 + 2][wq]);
                v.w = f2bf(buf[cq * 4 + 3][wq]);
            }
            *(us4*)&dst[(((long)b * PH + hp) * PH + wp) * CH + ci0 + cq * 4] = v;
        }
        __syncthreads();
    }
}

// ---------------------------------------------------------------------------
// K6: gated 3x3 conv, implicit bf16 MFMA GEMM, depth-2 counted-vmcnt pipeline.
//   Loop invariant: 12 vm-ops outstanding per wave at entry (bufs kc, kc+1).
//   wait vmcnt(6) -> own 6 loads of buf[cur] done; s_barrier -> ALL waves'
//   loads of buf[cur] done (each waited before the barrier); compute;
//   lgkmcnt(0)+barrier -> all reads of buf[cur] done; STAGE kc+2 into it.
// ---------------------------------------------------------------------------
__global__ __launch_bounds__(256, 2)
void conv_gemm(const unsigned short* __restrict__ xp3,
               const unsigned short* __restrict__ xp4,
               const unsigned short* __restrict__ Wp0,
               const float* __restrict__ gates,
               const float* __restrict__ bias2,
               const float* __restrict__ x3,
               const float* __restrict__ x4,
               float* __restrict__ outg) {
    int zc = blockIdx.y;
    const unsigned short* xp = zc ? xp3 : xp4;
    const unsigned short* Wp = Wp0 + (long)zc * CH * KTOT;
    const float* gate  = gates + (long)zc * 2048;
    const float* bias  = bias2 + zc * CH;
    const float* resid = zc ? x4 : x3;
    float* out = outg + (long)zc * OUTHALF;

    __shared__ short As[2][4 * 128 * 8];   // 2 x 8 KB
    __shared__ short Bs[2][4 * 256 * 8];   // 2 x 16 KB
    int tid = threadIdx.x;
    // XCD-chunked bijective swizzle (576 % 8 == 0): XCD k owns image k.
    int bm0 = blockIdx.x;
    int bm = (bm0 & 7) * 72 + (bm0 >> 3);
    int bimg = bm / 72, tt = bm - bimg * 72;
    int h0 = (tt / 6) * 8, w0 = (tt % 6) * 16;

    int lane = tid & 63, wid = tid >> 6;
    int wm = wid & 1, wn = wid >> 1;
    int lm = lane & 15, quad = lane >> 4;

    long apix0 = ((long)(bimg * PH + h0 + (lane >> 4)) * PH + (w0 + (lane & 15))) * CH + wid * 8;
    long apix1 = ((long)(bimg * PH + h0 + 4 + (lane >> 4)) * PH + (w0 + (lane & 15))) * CH + wid * 8;
    long bb0 = (long)(lane) * KTOT + wid * 8;
    long bb1 = (long)(64 + lane) * KTOT + wid * 8;
    long bb2 = (long)(128 + lane) * KTOT + wid * 8;
    long bb3 = (long)(192 + lane) * KTOT + wid * 8;

    float4f acc[4][8] = {};

    auto STAGE = [&](int buf, int kc) {
        int r9 = kc >> 3;
        int dy = r9 / 3, dx = r9 - dy * 3;
        long aoff = (long)(dy * PH + dx) * CH + ((kc & 7) << 5);
        long boff = (long)kc << 5;
        short* asd = &As[buf][wid * 1024];
        short* bsd = &Bs[buf][wid * 2048];
        GLDS16(xp + apix0 + aoff, asd);
        GLDS16(xp + apix1 + aoff, asd + 512);
        GLDS16(Wp + bb0 + boff, bsd);
        GLDS16(Wp + bb1 + boff, bsd + 512);
        GLDS16(Wp + bb2 + boff, bsd + 1024);
        GLDS16(Wp + bb3 + boff, bsd + 1536);
    };

    STAGE(0, 0);
    STAGE(1, 1);
    int cur = 0;
    for (int kc = 0; kc < NCHUNK; ++kc) {
        if (kc + 1 < NCHUNK) {
            asm volatile("s_waitcnt vmcnt(6)\n\ts_barrier" ::: "memory");
        } else {
            asm volatile("s_waitcnt vmcnt(0)\n\ts_barrier" ::: "memory");
        }
        short8 af[4], bfr[8];
#pragma unroll
        for (int i = 0; i < 4; ++i)
            af[i] = *(short8*)&As[cur][quad * 1024 + (wm * 64 + i * 16 + lm) * 8];
#pragma unroll
        for (int j = 0; j < 8; ++j)
            bfr[j] = *(short8*)&Bs[cur][quad * 2048 + (wn * 128 + j * 16 + lm) * 8];
#pragma unroll
        for (int i = 0; i < 4; ++i)
#pragma unroll
            for (int j = 0; j < 8; ++j)
                acc[i][j] = __builtin_amdgcn_mfma_f32_16x16x32_bf16(af[i], bfr[j], acc[i][j], 0, 0, 0);
        asm volatile("s_waitcnt lgkmcnt(0)\n\ts_barrier" ::: "memory");
        if (kc + 2 < NCHUNK) STAGE(cur, kc + 2);
        cur ^= 1;
    }

    // epilogue: D row = quad*4+reg (pixel w-offset), col = lane&15 (co)
#pragma unroll
    for (int j = 0; j < 8; ++j) {
        int co = wn * 128 + j * 16 + lm;
        float g  = gate[bimg * CH + co];
        float bv = bias[co];
#pragma unroll
        for (int i = 0; i < 4; ++i) {
            int h = h0 + wm * 4 + i;
            int w = w0 + quad * 4;
            long o = ((long)(bimg * CH + co)) * HWA + h * WW + w;
            float4f rv = *(const float4f*)(resid + o);
            float4f ov = rv + g * (acc[i][j] + bv);
            *(float4f*)(out + o) = ov;
        }
    }
}

// ---------------------------------------------------------------------------
extern "C" void kernel_launch(void* const* d_in, const int* in_sizes, int n_in,
                              void* d_out, int out_size, void* d_ws, size_t ws_size,
                              hipStream_t stream) {
    const float* x1 = (const float*)d_in[0];
    const float* x2 = (const float*)d_in[1];
    const float* x3 = (const float*)d_in[2];
    const float* x4 = (const float*)d_in[3];
    const float* conv3_w = (const float*)d_in[4];
    const float* conv3_b = (const float*)d_in[5];
    const float* bn3_g = (const float*)d_in[6];
    const float* bn3_b = (const float*)d_in[7];
    const float* bn3_m = (const float*)d_in[8];
    const float* bn3_v = (const float*)d_in[9];
    const float* conv4_w = (const float*)d_in[10];
    const float* conv4_b = (const float*)d_in[11];
    const float* bn4_g = (const float*)d_in[12];
    const float* bn4_b = (const float*)d_in[13];
    const float* bn4_m = (const float*)d_in[14];
    const float* bn4_v = (const float*)d_in[15];
    const float* conv1_w = (const float*)d_in[16];
    const float* conv1_b = (const float*)d_in[17];
    const float* bn1_g = (const float*)d_in[18];
    const float* bn1_b = (const float*)d_in[19];
    const float* bn1_m = (const float*)d_in[20];
    const float* bn1_v = (const float*)d_in[21];
    const float* conv2_w = (const float*)d_in[22];
    const float* conv2_b = (const float*)d_in[23];
    const float* bn2_g = (const float*)d_in[24];
    const float* bn2_b = (const float*)d_in[25];
    const float* bn2_m = (const float*)d_in[26];
    const float* bn2_v = (const float*)d_in[27];
    const float* fc1_w = (const float*)d_in[28];
    const float* fc1_b = (const float*)d_in[29];
    const float* fc2_w = (const float*)d_in[30];
    const float* fc2_b = (const float*)d_in[31];
    const float* fc3_w1 = (const float*)d_in[32];
    const float* fc3_b1 = (const float*)d_in[33];
    const float* fc3_w2 = (const float*)d_in[34];
    const float* fc3_b2 = (const float*)d_in[35];

    float* ws = (float*)d_ws;
    float* px    = ws;                 // 2*8*256*57 = 233472 floats
    float* y     = ws + 233472;        // 233472 floats
    float* gates = ws + 466944;        // 2*8*256 = 4096
    float* bias  = ws + 471040;        // 2*256 = 512
    unsigned short* Wp  = (unsigned short*)(ws + 471552);   // 2*256*2304 shorts
    unsigned short* xp3 = Wp + 2 * CH * KTOT;               // 8*98*98*256 shorts
    unsigned short* xp4 = xp3 + (long)BATCH * PH * PH * CH;

    pool_kernel<<<dim3(256, 8, 2), 256, 0, stream>>>(x1, x2, px);
    ycomp_kernel<<<dim3(57, 8, 2), 256, 0, stream>>>(px,
        conv3_w, conv3_b, bn3_g, bn3_b, bn3_m, bn3_v,
        conv4_w, conv4_b, bn4_g, bn4_b, bn4_m, bn4_v, y);
    attn_kernel<<<dim3(8), 256, 0, stream>>>(y, fc1_w, fc1_b, fc2_w, fc2_b,
        fc3_w1, fc3_b1, fc3_w2, fc3_b2, gates);
    prepack_kernel<<<dim3(4608), 256, 0, stream>>>(
        conv1_w, conv1_b, bn1_g, bn1_b, bn1_m, bn1_v,
        conv2_w, conv2_b, bn2_g, bn2_b, bn2_m, bn2_v, Wp, bias);
    pad_kernel<<<dim3(PH, 8, 2), 256, 0, stream>>>(x3, x4, xp3, xp4);

    // z=0: x3_out = x3 + gate1*BN1(conv1(x4)); z=1: x4_out = x4 + gate2*BN2(conv2(x3))
    conv_gemm<<<dim3(576, 2), 256, 0, stream>>>(xp3, xp4, Wp, gates, bias,
        x3, x4, (float*)d_out);
}

// Round 7
// 815.011 us; speedup vs baseline: 1.4631x; 1.1412x over previous
//
#include <hip/hip_runtime.h>

// ---------------------------------------------------------------------------
// Structure_Diffusion: pooled-token attention gates + two gated 3x3 convs.
//  R4 counters: conv_gemm 389us, Mfma 18.3%, HBM 15.5%, 0 bank conflicts.
//  Diagnosis: TA line-transaction bound — every staging lane hit a distinct
//  64B line (A stride 512B, B stride 4608B): 1536 lines/block-iter, 4x
//  byte overfetch.  R5: consumption-ordered global layouts.
//   Wp2[kc][quad][co][8]  -> B staging = contiguous 1KB per instr
//   xp2[b][cq8][hp][wp][8] -> A staging = 4x256B contiguous runs per instr
//  LDS image + ds_read + MFMA addressing byte-identical to R4.
//  (R7 = R5 resubmitted verbatim after 2x GPU timeout; algebra re-audited.)
// ---------------------------------------------------------------------------

#define BATCH 8
#define CH    256
#define HH    96
#define WW    96
#define HWA   9216      // 96*96
#define NP    57
#define PH    98        // padded spatial
#define KTOT  2304      // 9*256
#define NCHUNK 72       // KTOT/32
#define OUTHALF (BATCH*CH*HWA)  // 18874368
#define YSTR  260       // y row stride in attn LDS (16B-aligned)
#define XPP   (PH*PH*8) // 76832 shorts per (b,cq) plane

typedef short  short8  __attribute__((ext_vector_type(8)));
typedef float  float4f __attribute__((ext_vector_type(4)));
typedef unsigned short us4 __attribute__((ext_vector_type(4)));
typedef unsigned short us8 __attribute__((ext_vector_type(8)));

__device__ __forceinline__ unsigned short f2bf(float f) {
    unsigned int u = __float_as_uint(f);
    u += 0x7fffu + ((u >> 16) & 1u);   // RNE
    return (unsigned short)(u >> 16);
}

#define GLDS16(gp, sp) __builtin_amdgcn_global_load_lds( \
    (const __attribute__((address_space(1))) void*)(gp),  \
    (__attribute__((address_space(3))) void*)(sp), 16, 0, 0)

// ---------------------------------------------------------------------------
// K1: pool x1/x2 into 57 block-means per (b,c).  grid (256 c, 8 b, 2 input)
// ---------------------------------------------------------------------------
__global__ void pool_kernel(const float* __restrict__ x1,
                            const float* __restrict__ x2,
                            float* __restrict__ px) {
    int c = blockIdx.x, b = blockIdx.y, z = blockIdx.z;
    const float* src = (z ? x2 : x1) + ((long)b * CH + c) * HWA;
    __shared__ float seg[1152];   // [row 96][colblock 12]
    __shared__ float bins[144];   // 12x12 grid of 8x8 block sums
    int t = threadIdx.x;
    for (int s = t; s < 1152; s += 256) {
        int r = s / 12, cb = s - r * 12;
        const float4f* p = (const float4f*)(src + r * 96 + cb * 8);
        float4f a = p[0], bv = p[1];
        seg[s] = (a.x + a.y) + (a.z + a.w) + (bv.x + bv.y) + (bv.z + bv.w);
    }
    __syncthreads();
    if (t < 144) {
        int i = t / 12, j = t - i * 12;
        float s = 0.f;
#pragma unroll
        for (int r = 0; r < 8; ++r) s += seg[(i * 8 + r) * 12 + j];
        bins[t] = s;
    }
    __syncthreads();
    if (t < NP) {
        int bh0, bw0, nb;
        if (t == 0)      { bh0 = 0; bw0 = 0; nb = 12; }
        else if (t < 5)  { int q = t - 1;  bh0 = (q >> 1) * 6; bw0 = (q & 1) * 6; nb = 6; }
        else if (t < 21) { int q = t - 5;  bh0 = (q >> 2) * 3; bw0 = (q & 3) * 3; nb = 3; }
        else             { int q = t - 21; bh0 = (q / 6) * 2;  bw0 = (q % 6) * 2; nb = 2; }
        float s = 0.f;
        for (int i = 0; i < nb; ++i)
            for (int j = 0; j < nb; ++j)
                s += bins[(bh0 + i) * 12 + (bw0 + j)];
        px[(((long)z * BATCH + b) * CH + c) * NP + t] = s / (float)(nb * nb * 64);
    }
}

// ---------------------------------------------------------------------------
// K2: y[z,b,n,c] = normalize_c( BN(conv1x1(px)) ).  grid (57 n, 8 b, 2 z)
// ---------------------------------------------------------------------------
__global__ void ycomp_kernel(const float* __restrict__ px,
    const float* __restrict__ w3, const float* __restrict__ cb3,
    const float* __restrict__ g3, const float* __restrict__ be3,
    const float* __restrict__ m3, const float* __restrict__ v3,
    const float* __restrict__ w4, const float* __restrict__ cb4,
    const float* __restrict__ g4, const float* __restrict__ be4,
    const float* __restrict__ m4, const float* __restrict__ v4,
    float* __restrict__ y) {
    int n = blockIdx.x, b = blockIdx.y, z = blockIdx.z;
    __shared__ float col[CH];
    __shared__ float red[CH];
    int c = threadIdx.x;
    col[c] = px[(((long)z * BATCH + b) * CH + c) * NP + n];
    __syncthreads();
    const float* w  = z ? w4  : w3;
    const float* cb = z ? cb4 : cb3;
    const float* gg = z ? g4  : g3;
    const float* be = z ? be4 : be3;
    const float* mm = z ? m4  : m3;
    const float* vv = z ? v4  : v3;
    float s = gg[c] * rsqrtf(vv[c] + 1e-5f);
    const float4f* wr4  = (const float4f*)(w + (long)c * CH);
    const float4f* col4 = (const float4f*)col;
    float4f a4 = {0.f, 0.f, 0.f, 0.f};
#pragma unroll 8
    for (int ci = 0; ci < CH / 4; ++ci) a4 += wr4[ci] * col4[ci];
    float acc = (a4.x + a4.y) + (a4.z + a4.w);
    float yv = s * acc + (cb[c] - mm[c]) * s + be[c];
    red[c] = yv * yv;
    __syncthreads();
    for (int st = 128; st > 0; st >>= 1) {
        if (c < st) red[c] += red[c + st];
        __syncthreads();
    }
    float scale = 1.f / fmaxf(sqrtf(red[0]), 1e-12f);
    y[(((long)z * BATCH + b) * NP + n) * CH + c] = yv * scale;
}

// ---------------------------------------------------------------------------
// K3: per-batch attention + fc3 -> gates[2][8][256].  grid (8), 256 thr
// ---------------------------------------------------------------------------
__global__ void attn_kernel(const float* __restrict__ y,
    const float* __restrict__ fw1, const float* __restrict__ fb1,
    const float* __restrict__ fw2, const float* __restrict__ fb2,
    const float* __restrict__ w31, const float* __restrict__ b31,
    const float* __restrict__ w32, const float* __restrict__ b32,
    float* __restrict__ gates) {
    int b = blockIdx.x, t = threadIdx.x;
    __shared__ __align__(16) float y1s[NP * YSTR];
    __shared__ __align__(16) float y2s[NP * YSTR];
    __shared__ float l1[NP * NP];
    __shared__ float l2[NP * NP];
    __shared__ float w31s[16 * NP];
    __shared__ float W21[16 * NP];
    __shared__ float W22[16 * NP];
    const float* y1g = y + (long)b * NP * CH;
    const float* y2g = y + (long)(BATCH + b) * NP * CH;
    for (int i = t; i < NP * 64; i += 256) {     // 64 float4 per row
        int n = i >> 6, cq = i & 63;
        *(float4f*)&y1s[n * YSTR + cq * 4] = *(const float4f*)&y1g[n * CH + cq * 4];
        *(float4f*)&y2s[n * YSTR + cq * 4] = *(const float4f*)&y2g[n * CH + cq * 4];
    }
    for (int i = t; i < 16 * NP; i += 256) w31s[i] = w31[i];
    __syncthreads();
    float a10 = fw1[0], a11 = fw1[1], a12 = fw1[2], a13 = fw1[3], b1v = fb1[0];
    float a20 = fw2[0], a21 = fw2[1], a22 = fw2[2], a23 = fw2[3], b2v = fb2[0];
    int p0 = (t & 7) * 8;                        // bank-stagger start
    for (int idx = t; idx < NP * NP; idx += 256) {
        int n = idx / NP, m = idx - n * NP;
        const float4f* yn1 = (const float4f*)&y1s[n * YSTR];
        const float4f* ym1 = (const float4f*)&y1s[m * YSTR];
        const float4f* yn2 = (const float4f*)&y2s[n * YSTR];
        const float4f* ym2 = (const float4f*)&y2s[m * YSTR];
        float4f d1 = {0,0,0,0}, d2 = {0,0,0,0}, d12 = {0,0,0,0};
        for (int q = 0; q < 64; ++q) {
            int cq = (q + p0) & 63;
            float4f a1 = yn1[cq], bb1 = ym1[cq];
            float4f a2 = yn2[cq], bb2 = ym2[cq];
            d1 += a1 * bb1; d2 += a2 * bb2; d12 += a1 * bb2;
        }
        float dd1 = (d1.x + d1.y) + (d1.z + d1.w);
        float dd2 = (d2.x + d2.y) + (d2.z + d2.w);
        float dd12 = (d12.x + d12.y) + (d12.z + d12.w);
        float s1 = 1.f - dd1, s2 = 1.f - dd2, s12 = 1.f - dd12;
        l1[idx] = a10 * s1 + a11 * s2 + a12 * s1 * s2 + a13 * s12 + b1v;
        l2[idx] = a20 * s1 + a21 * s2 + a22 * s1 * s2 + a23 * s12 + b2v;
    }
    __syncthreads();
    if (t < 2 * NP) {    // softmax rows (both branches)
        int which = t >= NP;
        int n = which ? t - NP : t;
        float* l = which ? l2 : l1;
        float mx = -1e30f;
        for (int m = 0; m < NP; ++m) mx = fmaxf(mx, l[n * NP + m]);
        float sum = 0.f;
        for (int m = 0; m < NP; ++m) { float e = __expf(l[n * NP + m] - mx); l[n * NP + m] = e; sum += e; }
        float inv = 1.f / sum;
        for (int m = 0; m < NP; ++m) l[n * NP + m] *= inv;
    }
    __syncthreads();
    // W2[k][m] = sum_n w31[k][n] * l[n][m]
    for (int i = t; i < 16 * NP; i += 256) {
        int k = i / NP, m = i - k * NP;
        float s1 = 0.f, s2 = 0.f;
        for (int n = 0; n < NP; ++n) {
            float wv = w31s[k * NP + n];
            s1 += wv * l1[n * NP + m];
            s2 += wv * l2[n * NP + m];
        }
        W21[i] = s1; W22[i] = s2;
    }
    __syncthreads();
    int c = t;
    float h1[16], h2[16];
#pragma unroll
    for (int k = 0; k < 16; ++k) { h1[k] = 0.f; h2[k] = 0.f; }
    for (int m = 0; m < NP; ++m) {
        float ym1 = y1s[m * YSTR + c];
        float ym2 = y2s[m * YSTR + c];
#pragma unroll
        for (int k = 0; k < 16; ++k) {
            h1[k] += W21[k * NP + m] * ym1;
            h2[k] += W22[k * NP + m] * ym2;
        }
    }
    float o1 = b32[0], o2 = b32[0];
#pragma unroll
    for (int k = 0; k < 16; ++k) {
        float wk = w32[k];
        o1 += wk * (h1[k] + b31[k]);
        o2 += wk * (h2[k] + b31[k]);
    }
    gates[b * CH + c]        = 1.f / (1.f + __expf(-o1));
    gates[2048 + b * CH + c] = 1.f / (1.f + __expf(-o2));
}

// ---------------------------------------------------------------------------
// K4: prepack -> Wp2[which][kc][quad][co][8] bf16 (BN folded), bias.
//     dest-major decode; kc = tap*8 + cblock, quad = 8-ch group in 32-chunk.
// ---------------------------------------------------------------------------
__global__ void prepack_kernel(
    const float* __restrict__ w1, const float* __restrict__ cb1,
    const float* __restrict__ g1, const float* __restrict__ be1,
    const float* __restrict__ m1, const float* __restrict__ v1,
    const float* __restrict__ w2, const float* __restrict__ cb2,
    const float* __restrict__ g2, const float* __restrict__ be2,
    const float* __restrict__ m2, const float* __restrict__ v2,
    unsigned short* __restrict__ Wp, float* __restrict__ bias) {
    long idx = (long)blockIdx.x * 256 + threadIdx.x;   // 0 .. 2*589824-1
    int which = idx >= (long)CH * KTOT;
    long rem = idx - (long)which * CH * KTOT;
    int kc   = (int)(rem >> 13);          // /8192 (=4*256*8)
    int r2   = (int)(rem & 8191);
    int quad = r2 >> 11;                  // /2048 (=256*8)
    int r3   = r2 & 2047;
    int co   = r3 >> 3;
    int e    = r3 & 7;
    int cb_  = kc & 7, r = kc >> 3;
    int ci   = cb_ * 32 + quad * 8 + e;
    int dy = r / 3, dx = r - dy * 3;
    const float* w  = which ? w2  : w1;
    const float* cb = which ? cb2 : cb1;
    const float* gg = which ? g2  : g1;
    const float* be = which ? be2 : be1;
    const float* mm = which ? m2  : m1;
    const float* vv = which ? v2  : v1;
    float s = gg[co] * rsqrtf(vv[co] + 1e-5f);
    float val = w[(((long)co * CH + ci) * 3 + dy) * 3 + dx] * s;
    Wp[idx] = f2bf(val);
    if (kc == 0 && quad == 0 && e == 0)
        bias[which * CH + co] = (cb[co] - mm[co]) * s + be[co];
}

// ---------------------------------------------------------------------------
// K5: pad+transpose x3/x4 -> xp2[b][cq8 0..31][hp][wp][8ch] bf16.
//     grid (98 hp, 8 b, 2 which).  us8 (16B/lane) fully-coalesced writes.
// ---------------------------------------------------------------------------
__global__ void pad_kernel(const float* __restrict__ x3,
                           const float* __restrict__ x4,
                           unsigned short* __restrict__ xp3,
                           unsigned short* __restrict__ xp4) {
    int hp = blockIdx.x, b = blockIdx.y, z = blockIdx.z;
    const float* src = z ? x4 : x3;
    unsigned short* dst = z ? xp4 : xp3;
    __shared__ float buf[64][97];
    int t = threadIdx.x;
    bool border = (hp == 0 || hp == PH - 1);
    int h = hp - 1;
    for (int ci0 = 0; ci0 < CH; ci0 += 64) {
        if (!border) {
            for (int idx = t; idx < 64 * 96; idx += 256) {
                int cl = idx / 96, w = idx - cl * 96;
                buf[cl][w] = src[(((long)b * CH + ci0 + cl) * HH + h) * WW + w];
            }
        }
        __syncthreads();
        // 8 channel-groups x 98 wp; lane-consecutive wp -> contiguous 16B writes
        for (int idx = t; idx < 8 * PH; idx += 256) {
            int cg = idx / PH, wp = idx - cg * PH;
            us8 v = {0, 0, 0, 0, 0, 0, 0, 0};
            if (!border && wp >= 1 && wp <= 96) {
                int wq = wp - 1;
#pragma unroll
                for (int j = 0; j < 8; ++j) v[j] = f2bf(buf[cg * 8 + j][wq]);
            }
            long o = (((long)b * 32 + (ci0 >> 3) + cg) * PH + hp) * PH + wp;
            *(us8*)&dst[o * 8] = v;
        }
        __syncthreads();
    }
}

// ---------------------------------------------------------------------------
// K6: gated 3x3 conv, implicit bf16 MFMA GEMM, depth-2 counted-vmcnt pipeline,
//     consumption-ordered layouts (A: 4x256B runs, B: contiguous 1KB/instr).
//   LDS As[quad][128 pix][8], Bs[quad][256 co][8] — identical to R4.
// ---------------------------------------------------------------------------
__global__ __launch_bounds__(256, 2)
void conv_gemm(const unsigned short* __restrict__ xp3,
               const unsigned short* __restrict__ xp4,
               const unsigned short* __restrict__ Wp0,
               const float* __restrict__ gates,
               const float* __restrict__ bias2,
               const float* __restrict__ x3,
               const float* __restrict__ x4,
               float* __restrict__ outg) {
    int zc = blockIdx.y;
    const unsigned short* xp = zc ? xp3 : xp4;
    const unsigned short* Wp = Wp0 + (long)zc * CH * KTOT;
    const float* gate  = gates + (long)zc * 2048;
    const float* bias  = bias2 + zc * CH;
    const float* resid = zc ? x4 : x3;
    float* out = outg + (long)zc * OUTHALF;

    __shared__ short As[2][4 * 128 * 8];   // 2 x 8 KB
    __shared__ short Bs[2][4 * 256 * 8];   // 2 x 16 KB
    int tid = threadIdx.x;
    // XCD-chunked bijective swizzle (576 % 8 == 0): XCD k owns image k.
    int bm0 = blockIdx.x;
    int bm = (bm0 & 7) * 72 + (bm0 >> 3);
    int bimg = bm / 72, tt = bm - bimg * 72;
    int h0 = (tt / 6) * 8, w0 = (tt % 6) * 16;

    int lane = tid & 63, wid = tid >> 6;
    int wm = wid & 1, wn = wid >> 1;
    int lm = lane & 15, quad = lane >> 4;

    // A: xp2[b][cq][hp][wp][8]; wave wid owns k-quad wid.
    // per-lane pixel: row = h0 + (lane>>4), col = w0 + (lane&15)
    long apix0 = ((((long)bimg * 32 + wid) * PH + (h0 + (lane >> 4))) * PH + (w0 + (lane & 15))) * 8;
    long apix1 = apix0 + (long)4 * PH * 8;
    // B: Wp2[kc][quad][co][8]; wave wid stages quad wid, 4x contiguous 1KB.
    long bbase = (long)wid * 2048 + (long)lane * 8;

    float4f acc[4][8] = {};

    auto STAGE = [&](int buf, int kc) {
        int r9 = kc >> 3;
        int dy = r9 / 3, dx = r9 - dy * 3;
        long aoff = (long)(kc & 7) * 4 * XPP + (long)(dy * PH + dx) * 8;
        long boff = (long)kc * 8192 + bbase;
        short* asd = &As[buf][wid * 1024];
        short* bsd = &Bs[buf][wid * 2048];
        GLDS16(xp + apix0 + aoff, asd);
        GLDS16(xp + apix1 + aoff, asd + 512);
        GLDS16(Wp + boff,        bsd);
        GLDS16(Wp + boff + 512,  bsd + 512);
        GLDS16(Wp + boff + 1024, bsd + 1024);
        GLDS16(Wp + boff + 1536, bsd + 1536);
    };

    STAGE(0, 0);
    STAGE(1, 1);
    int cur = 0;
    for (int kc = 0; kc < NCHUNK; ++kc) {
        if (kc + 1 < NCHUNK) {
            asm volatile("s_waitcnt vmcnt(6)\n\ts_barrier" ::: "memory");
        } else {
            asm volatile("s_waitcnt vmcnt(0)\n\ts_barrier" ::: "memory");
        }
        short8 af[4], bfr[8];
#pragma unroll
        for (int i = 0; i < 4; ++i)
            af[i] = *(short8*)&As[cur][quad * 1024 + (wm * 64 + i * 16 + lm) * 8];
#pragma unroll
        for (int j = 0; j < 8; ++j)
            bfr[j] = *(short8*)&Bs[cur][quad * 2048 + (wn * 128 + j * 16 + lm) * 8];
#pragma unroll
        for (int i = 0; i < 4; ++i)
#pragma unroll
            for (int j = 0; j < 8; ++j)
                acc[i][j] = __builtin_amdgcn_mfma_f32_16x16x32_bf16(af[i], bfr[j], acc[i][j], 0, 0, 0);
        asm volatile("s_waitcnt lgkmcnt(0)\n\ts_barrier" ::: "memory");
        if (kc + 2 < NCHUNK) STAGE(cur, kc + 2);
        cur ^= 1;
    }

    // epilogue: D row = quad*4+reg (pixel w-offset), col = lane&15 (co)
#pragma unroll
    for (int j = 0; j < 8; ++j) {
        int co = wn * 128 + j * 16 + lm;
        float g  = gate[bimg * CH + co];
        float bv = bias[co];
#pragma unroll
        for (int i = 0; i < 4; ++i) {
            int h = h0 + wm * 4 + i;
            int w = w0 + quad * 4;
            long o = ((long)(bimg * CH + co)) * HWA + h * WW + w;
            float4f rv = *(const float4f*)(resid + o);
            float4f ov = rv + g * (acc[i][j] + bv);
            *(float4f*)(out + o) = ov;
        }
    }
}

// ---------------------------------------------------------------------------
extern "C" void kernel_launch(void* const* d_in, const int* in_sizes, int n_in,
                              void* d_out, int out_size, void* d_ws, size_t ws_size,
                              hipStream_t stream) {
    const float* x1 = (const float*)d_in[0];
    const float* x2 = (const float*)d_in[1];
    const float* x3 = (const float*)d_in[2];
    const float* x4 = (const float*)d_in[3];
    const float* conv3_w = (const float*)d_in[4];
    const float* conv3_b = (const float*)d_in[5];
    const float* bn3_g = (const float*)d_in[6];
    const float* bn3_b = (const float*)d_in[7];
    const float* bn3_m = (const float*)d_in[8];
    const float* bn3_v = (const float*)d_in[9];
    const float* conv4_w = (const float*)d_in[10];
    const float* conv4_b = (const float*)d_in[11];
    const float* bn4_g = (const float*)d_in[12];
    const float* bn4_b = (const float*)d_in[13];
    const float* bn4_m = (const float*)d_in[14];
    const float* bn4_v = (const float*)d_in[15];
    const float* conv1_w = (const float*)d_in[16];
    const float* conv1_b = (const float*)d_in[17];
    const float* bn1_g = (const float*)d_in[18];
    const float* bn1_b = (const float*)d_in[19];
    const float* bn1_m = (const float*)d_in[20];
    const float* bn1_v = (const float*)d_in[21];
    const float* conv2_w = (const float*)d_in[22];
    const float* conv2_b = (const float*)d_in[23];
    const float* bn2_g = (const float*)d_in[24];
    const float* bn2_b = (const float*)d_in[25];
    const float* bn2_m = (const float*)d_in[26];
    const float* bn2_v = (const float*)d_in[27];
    const float* fc1_w = (const float*)d_in[28];
    const float* fc1_b = (const float*)d_in[29];
    const float* fc2_w = (const float*)d_in[30];
    const float* fc2_b = (const float*)d_in[31];
    const float* fc3_w1 = (const float*)d_in[32];
    const float* fc3_b1 = (const float*)d_in[33];
    const float* fc3_w2 = (const float*)d_in[34];
    const float* fc3_b2 = (const float*)d_in[35];

    float* ws = (float*)d_ws;
    float* px    = ws;                 // 2*8*256*57 = 233472 floats
    float* y     = ws + 233472;        // 233472 floats
    float* gates = ws + 466944;        // 2*8*256 = 4096
    float* bias  = ws + 471040;        // 2*256 = 512
    unsigned short* Wp  = (unsigned short*)(ws + 471552);   // 2*256*2304 shorts
    unsigned short* xp3 = Wp + 2 * CH * KTOT;               // 8*32*98*98*8 shorts
    unsigned short* xp4 = xp3 + (long)BATCH * 32 * XPP;

    pool_kernel<<<dim3(256, 8, 2), 256, 0, stream>>>(x1, x2, px);
    ycomp_kernel<<<dim3(57, 8, 2), 256, 0, stream>>>(px,
        conv3_w, conv3_b, bn3_g, bn3_b, bn3_m, bn3_v,
        conv4_w, conv4_b, bn4_g, bn4_b, bn4_m, bn4_v, y);
    attn_kernel<<<dim3(8), 256, 0, stream>>>(y, fc1_w, fc1_b, fc2_w, fc2_b,
        fc3_w1, fc3_b1, fc3_w2, fc3_b2, gates);
    prepack_kernel<<<dim3(4608), 256, 0, stream>>>(
        conv1_w, conv1_b, bn1_g, bn1_b, bn1_m, bn1_v,
        conv2_w, conv2_b, bn2_g, bn2_b, bn2_m, bn2_v, Wp, bias);
    pad_kernel<<<dim3(PH, 8, 2), 256, 0, stream>>>(x3, x4, xp3, xp4);

    // z=0: x3_out = x3 + gate1*BN1(conv1(x4)); z=1: x4_out = x4 + gate2*BN2(conv2(x3))
    conv_gemm<<<dim3(576, 2), 256, 0, stream>>>(xp3, xp4, Wp, gates, bias,
        x3, x4, (float*)d_out);
}